// Round 1
// baseline (663.904 us; speedup 1.0000x reference)
//
#include <hip/hip_runtime.h>

// CP reconstruction out[i,j,k] = sum_p A[i,p]*B[j,p]*C[k,p]
// GEMM: out[i, jk] = sum_p A[i,p] * KR[jk,p], KR[jk,p] = B[jk/50,p]*C[jk%50,p]
// Round 3: write-phase-bound fix.
//  (1) Swapped MFMA operands: D[jk][i] = KR * A^T. D-layout row=quad*4+reg now
//      runs along jk -> each lane's 4 acc regs are contiguous jk -> float4
//      stores (8 dwordx4/thread instead of 32 dword).
//  (2) One block per jk-tile, loops over all 5 i-tiles: KR staged ONCE, single
//      barrier, barrier-free i-loop -> stores of tile t overlap A-load/MFMA of
//      tile t+1 (continuous write stream, no phase bunching). 1600 blocks.
//  (3) Nontemporal stores (streaming output, never re-read).

typedef __attribute__((ext_vector_type(8))) short bf16x8;
typedef __attribute__((ext_vector_type(4))) float f32x4;
typedef __attribute__((ext_vector_type(4))) unsigned short u16x4;

#define I_DIM 600
#define J_DIM 4096
#define K_DIM 50
#define R_DIM 100
#define NJK (J_DIM * K_DIM)   // 204800
#define NT 128                // jk tile per block
#define MT 128                // i tile per loop iteration
#define NIT 5                 // i-tile iterations: ceil(600/128)
#define LDK 136               // KR LDS row stride (bf16 elems): 272B -> 2-way-free reads

__device__ __forceinline__ unsigned short f2bf(float x) {
    union { float f; unsigned int u; } v;
    v.f = x;
    unsigned int r = v.u + 0x7FFFu + ((v.u >> 16) & 1u);
    return (unsigned short)(r >> 16);
}

__global__ __launch_bounds__(512, 4) void cp_mfma_kernel(
    const float* __restrict__ A, const float* __restrict__ B,
    const float* __restrict__ C, float* __restrict__ out)
{
    __shared__ __align__(16) unsigned short Ks[NT * LDK];   // 34816 B

    const int tid = threadIdx.x;
    const int n0 = blockIdx.x * NT;   // jk tile origin
    const int lane = tid & 63;
    const int wave = tid >> 6;        // 0..7
    const int wjk = (wave & 1) * 64;  // wave jk-offset in tile: 0/64
    const int wi  = (wave >> 1) * 32; // wave i-offset in i-tile: 0/32/64/96
    const int ln = lane & 15;
    const int quad = lane >> 4;

    // ---- KR staging, ONCE per block: Ks[n][p] = bf16(B[j,p]*C[k,p]) ----
    #pragma unroll 4
    for (int it = 0; it < 8; ++it) {
        const int idx = tid + it * 512;
        const int p4 = idx & 31;        // which float4 along p (0..31)
        const int n = idx >> 5;         // jk row within tile (0..127)
        const int jk = n0 + n;
        const int j = jk / K_DIM;
        const int k = jk - j * K_DIM;
        float4 b4, c4;
        if (p4 < 25) {                  // p = p4*4 .. p4*4+3 < 100
            b4 = *(const float4*)(B + j * R_DIM + p4 * 4);
            c4 = *(const float4*)(C + k * R_DIM + p4 * 4);
        } else {
            b4 = make_float4(0.f, 0.f, 0.f, 0.f);
            c4 = b4;
        }
        u16x4 w;
        w[0] = f2bf(b4.x * c4.x); w[1] = f2bf(b4.y * c4.y);
        w[2] = f2bf(b4.z * c4.z); w[3] = f2bf(b4.w * c4.w);
        *(u16x4*)&Ks[n * LDK + p4 * 4] = w;
    }
    __syncthreads();

    // per-lane output base: row (i-part w/o i0) = wi + ln, col = n0+wjk+quad*4
    float* const obase = out + (long)(wi + ln) * NJK + (n0 + wjk + quad * 4);

    #pragma unroll 1
    for (int t = 0; t < NIT; ++t) {
        const int i0 = t * MT;

        // ---- A fragments (B-operand): n = ln -> i row, k = quad*8 + j ----
        bf16x8 afrag[2][4];
        #pragma unroll
        for (int nf = 0; nf < 2; ++nf) {
            const int row = i0 + wi + nf * 16 + ln;
            const bool rv = row < I_DIM;
            const float* Ar = A + row * R_DIM;
            #pragma unroll
            for (int ks = 0; ks < 4; ++ks) {
                const int col = ks * 32 + quad * 8;
                float4 lo = (rv && col < R_DIM) ? *(const float4*)(Ar + col)
                                                : make_float4(0.f, 0.f, 0.f, 0.f);
                float4 hi = (rv && col + 4 < R_DIM) ? *(const float4*)(Ar + col + 4)
                                                    : make_float4(0.f, 0.f, 0.f, 0.f);
                bf16x8 f;
                f[0] = (short)f2bf(lo.x); f[1] = (short)f2bf(lo.y);
                f[2] = (short)f2bf(lo.z); f[3] = (short)f2bf(lo.w);
                f[4] = (short)f2bf(hi.x); f[5] = (short)f2bf(hi.y);
                f[6] = (short)f2bf(hi.z); f[7] = (short)f2bf(hi.w);
                afrag[nf][ks] = f;
            }
        }

        // ---- MFMA: acc[mf][nf] = D[jk-frag][i-frag], swapped operands ----
        f32x4 acc[4][2] = {};
        #pragma unroll
        for (int ks = 0; ks < 4; ++ks) {
            const int kc = ks * 32 + quad * 8;
            bf16x8 kr[4];
            #pragma unroll
            for (int mf = 0; mf < 4; ++mf)
                kr[mf] = *(const bf16x8*)&Ks[(wjk + mf * 16 + ln) * LDK + kc];
            #pragma unroll
            for (int mf = 0; mf < 4; ++mf) {
                #pragma unroll
                for (int nf = 0; nf < 2; ++nf)
                    acc[mf][nf] = __builtin_amdgcn_mfma_f32_16x16x32_bf16(
                        kr[mf], afrag[nf][ks], acc[mf][nf], 0, 0, 0);
            }
        }

        // ---- stores: lane regs run along jk -> one float4 per (mf,nf) ----
        const bool v0 = (i0 + wi + ln) < I_DIM;
        const bool v1 = (i0 + wi + 16 + ln) < I_DIM;
        float* p0 = obase + (long)i0 * NJK;
        float* p1 = p0 + 16 * NJK;
        #pragma unroll
        for (int mf = 0; mf < 4; ++mf) {
            if (v0) __builtin_nontemporal_store(acc[mf][0], (f32x4*)(p0 + mf * 16));
            if (v1) __builtin_nontemporal_store(acc[mf][1], (f32x4*)(p1 + mf * 16));
        }
    }
}

extern "C" void kernel_launch(void* const* d_in, const int* in_sizes, int n_in,
                              void* d_out, int out_size, void* d_ws, size_t ws_size,
                              hipStream_t stream) {
    const float* A = (const float*)d_in[0];
    const float* B = (const float*)d_in[1];
    const float* C = (const float*)d_in[2];
    float* out = (float*)d_out;
    cp_mfma_kernel<<<dim3(NJK / NT), dim3(512), 0, stream>>>(A, B, C, out);
}

// Round 6
// 591.154 us; speedup vs baseline: 1.1231x; 1.1231x over previous
//
#include <hip/hip_runtime.h>

// CP reconstruction out[i,j,k] = sum_p A[i,p]*B[j,p]*C[k,p]
// GEMM: out[i, jk] = sum_p A[i,p] * KR[jk,p], KR[jk,p] = B[jk/50,p]*C[jk%50,p]
// Round 5 (resubmit x3; rounds 2/4/5 all died on GPUAcquisitionTimeout):
// fix round-4 correctness bug — LDK=120 < 128 made the p4=30/31 zero-pad
// writes (elements 120..127) spill into row n+1's elements 0..7 (absmax 4.06).
// Restore LDK=136 (272B stride: 4-bank row rotation, 2-way free reads).
// Keeps round-4 structure: 256-thread blocks (MT=64), launch_bounds(256,4)
// -> 4 independent blocks/CU (139KB LDS of 160KB), swapped-operand MFMA
// (D[jk][i] -> contiguous-jk float4 stores), no in-block i-loop.

typedef __attribute__((ext_vector_type(8))) short bf16x8;
typedef __attribute__((ext_vector_type(4))) float f32x4;
typedef __attribute__((ext_vector_type(4))) unsigned short u16x4;

#define I_DIM 600
#define J_DIM 4096
#define K_DIM 50
#define R_DIM 100
#define NJK (J_DIM * K_DIM)   // 204800
#define NT 128                // jk tile per block
#define MT 64                 // i tile per block
#define LDK 136               // KR LDS row stride (bf16): 272B; must be >= 128

__device__ __forceinline__ unsigned short f2bf(float x) {
    union { float f; unsigned int u; } v;
    v.f = x;
    unsigned int r = v.u + 0x7FFFu + ((v.u >> 16) & 1u);
    return (unsigned short)(r >> 16);
}

__global__ __launch_bounds__(256, 4) void cp_mfma_kernel(
    const float* __restrict__ A, const float* __restrict__ B,
    const float* __restrict__ C, float* __restrict__ out)
{
    __shared__ __align__(16) unsigned short Ks[NT * LDK];   // 34816 B

    const int tid = threadIdx.x;
    const int n0 = blockIdx.x * NT;   // jk tile origin
    const int i0 = blockIdx.y * MT;   // i tile origin
    const int lane = tid & 63;
    const int wave = tid >> 6;        // 0..3
    const int wjk = (wave & 1) * 64;  // wave jk-offset: 0/64
    const int wi  = (wave >> 1) * 32; // wave i-offset: 0/32
    const int ln = lane & 15;
    const int quad = lane >> 4;

    // ---- KR staging: Ks[n][p] = bf16(B[j,p]*C[k,p]), 16 iters of 256 ----
    #pragma unroll 4
    for (int it = 0; it < 16; ++it) {
        const int idx = tid + it * 256;
        const int p4 = idx & 31;        // which float4 along p (0..31)
        const int n = idx >> 5;         // jk row within tile (0..127)
        const int jk = n0 + n;
        const int j = jk / K_DIM;
        const int k = jk - j * K_DIM;
        float4 b4, c4;
        if (p4 < 25) {                  // p = p4*4 .. p4*4+3 < 100
            b4 = *(const float4*)(B + j * R_DIM + p4 * 4);
            c4 = *(const float4*)(C + k * R_DIM + p4 * 4);
        } else {
            b4 = make_float4(0.f, 0.f, 0.f, 0.f);
            c4 = b4;
        }
        u16x4 w;
        w[0] = f2bf(b4.x * c4.x); w[1] = f2bf(b4.y * c4.y);
        w[2] = f2bf(b4.z * c4.z); w[3] = f2bf(b4.w * c4.w);
        *(u16x4*)&Ks[n * LDK + p4 * 4] = w;
    }

    // ---- A fragments (B-operand of swapped MFMA): n=ln -> i, k=quad*8+j ----
    bf16x8 afrag[2][4];
    #pragma unroll
    for (int nf = 0; nf < 2; ++nf) {
        const int row = i0 + wi + nf * 16 + ln;
        const bool rv = row < I_DIM;
        const float* Ar = A + row * R_DIM;
        #pragma unroll
        for (int ks = 0; ks < 4; ++ks) {
            const int col = ks * 32 + quad * 8;
            float4 lo = (rv && col < R_DIM) ? *(const float4*)(Ar + col)
                                            : make_float4(0.f, 0.f, 0.f, 0.f);
            float4 hi = (rv && col + 4 < R_DIM) ? *(const float4*)(Ar + col + 4)
                                                : make_float4(0.f, 0.f, 0.f, 0.f);
            bf16x8 f;
            f[0] = (short)f2bf(lo.x); f[1] = (short)f2bf(lo.y);
            f[2] = (short)f2bf(lo.z); f[3] = (short)f2bf(lo.w);
            f[4] = (short)f2bf(hi.x); f[5] = (short)f2bf(hi.y);
            f[6] = (short)f2bf(hi.z); f[7] = (short)f2bf(hi.w);
            afrag[nf][ks] = f;
        }
    }
    __syncthreads();

    // ---- MFMA: acc[mf][nf] = D[jk-frag][i-frag], swapped operands ----
    f32x4 acc[4][2] = {};
    #pragma unroll
    for (int ks = 0; ks < 4; ++ks) {
        const int kc = ks * 32 + quad * 8;
        bf16x8 kr[4];
        #pragma unroll
        for (int mf = 0; mf < 4; ++mf)
            kr[mf] = *(const bf16x8*)&Ks[(wjk + mf * 16 + ln) * LDK + kc];
        #pragma unroll
        for (int mf = 0; mf < 4; ++mf) {
            #pragma unroll
            for (int nf = 0; nf < 2; ++nf)
                acc[mf][nf] = __builtin_amdgcn_mfma_f32_16x16x32_bf16(
                    kr[mf], afrag[nf][ks], acc[mf][nf], 0, 0, 0);
        }
    }

    // ---- stores: lane regs run along jk -> one float4 per (mf,nf) ----
    float* const obase = out + (long)(i0 + wi + ln) * NJK + (n0 + wjk + quad * 4);
    const bool v0 = (i0 + wi + ln) < I_DIM;
    const bool v1 = (i0 + wi + 16 + ln) < I_DIM;
    float* p0 = obase;
    float* p1 = obase + 16 * (long)NJK;
    #pragma unroll
    for (int mf = 0; mf < 4; ++mf) {
        if (v0) *(f32x4*)(p0 + mf * 16) = acc[mf][0];
        if (v1) *(f32x4*)(p1 + mf * 16) = acc[mf][1];
    }
}

extern "C" void kernel_launch(void* const* d_in, const int* in_sizes, int n_in,
                              void* d_out, int out_size, void* d_ws, size_t ws_size,
                              hipStream_t stream) {
    const float* A = (const float*)d_in[0];
    const float* B = (const float*)d_in[1];
    const float* C = (const float*)d_in[2];
    float* out = (float*)d_out;
    dim3 grid(NJK / NT, (I_DIM + MT - 1) / MT);   // 1600 x 10
    cp_mfma_kernel<<<grid, dim3(256), 0, stream>>>(A, B, C, out);
}